// Round 2
// baseline (43288.434 us; speedup 1.0000x reference)
//
#include <hip/hip_runtime.h>
#include <stdint.h>

#define M_SEQ 8192
#define N_DIM 2048
#define N3    (3 * N_DIM)   // 6144

// Scan geometry: 128 persistent blocks x 256 threads. Block g owns h columns
// [g*16, g*16+16) => 48 gate-rows, 384 weight floats per thread (AGPR+VGPR).
#define NBLK  128
#define COLS  16            // h columns per block
#define RPW   12            // gate-rows per wave (48 rows / 4 waves)

typedef short bf16x8 __attribute__((ext_vector_type(8)));   // 8 bf16 in 4 VGPRs
typedef float f32x4  __attribute__((ext_vector_type(4)));
typedef unsigned short u16;
typedef unsigned long long u64;

// fp32 -> bf16, round-to-nearest-even
__device__ __forceinline__ u16 f2bf(float f) {
    unsigned int u = __builtin_bit_cast(unsigned int, f);
    u = (u + 0x7fffu + ((u >> 16) & 1u)) >> 16;
    return (u16)u;
}
__device__ __forceinline__ float bf2f(u16 v) {
    return __builtin_bit_cast(float, (unsigned int)v << 16);
}

// ---------------------------------------------------------------------------
// in [R][C] fp32 -> out [C][R] bf16  (tiled transpose)
__global__ void k_tr_bf16(const float* __restrict__ in, u16* __restrict__ out, int R, int C) {
    __shared__ float tile[32][33];
    const int tx = threadIdx.x & 31, ty = threadIdx.x >> 5;
    const int c = blockIdx.x * 32 + tx;
#pragma unroll
    for (int k = 0; k < 4; ++k)
        tile[ty + k * 8][tx] = in[(size_t)(blockIdx.y * 32 + ty + k * 8) * C + c];
    __syncthreads();
#pragma unroll
    for (int k = 0; k < 4; ++k)
        out[(size_t)(blockIdx.x * 32 + ty + k * 8) * R + blockIdx.y * 32 + tx] =
            f2bf(tile[tx][ty + k * 8]);
}

// in [R][C] fp32 -> out [C][R] fp32
__global__ void k_tr_f32(const float* __restrict__ in, float* __restrict__ out, int R, int C) {
    __shared__ float tile[32][33];
    const int tx = threadIdx.x & 31, ty = threadIdx.x >> 5;
    const int c = blockIdx.x * 32 + tx;
#pragma unroll
    for (int k = 0; k < 4; ++k)
        tile[ty + k * 8][tx] = in[(size_t)(blockIdx.y * 32 + ty + k * 8) * C + c];
    __syncthreads();
#pragma unroll
    for (int k = 0; k < 4; ++k)
        out[(size_t)(blockIdx.x * 32 + ty + k * 8) * R + blockIdx.y * 32 + tx] =
            tile[tx][ty + k * 8];
}

// zero BOTH h ping-pong buffers (tag 0 == legit step-0 state h0=0 for buf0;
// buf1 must not contain accidental tag==1 garbage from a dirty workspace).
__global__ void k_init(u64* hbuf) {
    int i = blockIdx.x * 256 + threadIdx.x;
    if (i < 2 * N_DIM) hbuf[i] = 0ull;
}

// ---------------------------------------------------------------------------
// gx = (bf16)x @ Wx + b : A [8192][2048] fp32 row-major (converted inline),
// B [6144][2048] bf16 (Wx^T), C [8192][6144] GXT. 128x128 tile, BK=32,
// 4 waves 2x2.
template <typename GXT>
__global__ __launch_bounds__(256) void k_gemm(const float* __restrict__ A,
                                              const u16* __restrict__ B,
                                              const float* __restrict__ bias,
                                              GXT* __restrict__ C) {
    __shared__ u16 As[128 * 32];
    __shared__ u16 Bs[128 * 32];
    const int tid = threadIdx.x, lane = tid & 63, wave = tid >> 6;
    const int m0 = blockIdx.y * 128, n0 = blockIdx.x * 128;
    const int wm = (wave >> 1) * 64, wn = (wave & 1) * 64;
    const int row0 = tid >> 2, ko0 = (tid & 3) * 8;   // 8 elems (16B bf16) per thread/half

    f32x4 acc[4][4] = {};

    for (int k0 = 0; k0 < N_DIM; k0 += 32) {
        // A: fp32 source, convert to bf16 in-register
        const float* ap0 = A + (size_t)(m0 + row0) * N_DIM + k0 + ko0;
        const float* ap1 = A + (size_t)(m0 + 64 + row0) * N_DIM + k0 + ko0;
        float4 a0l = *(const float4*)(ap0), a0h = *(const float4*)(ap0 + 4);
        float4 a1l = *(const float4*)(ap1), a1h = *(const float4*)(ap1 + 4);
        bf16x8 a0, a1;
        a0[0] = (short)f2bf(a0l.x); a0[1] = (short)f2bf(a0l.y);
        a0[2] = (short)f2bf(a0l.z); a0[3] = (short)f2bf(a0l.w);
        a0[4] = (short)f2bf(a0h.x); a0[5] = (short)f2bf(a0h.y);
        a0[6] = (short)f2bf(a0h.z); a0[7] = (short)f2bf(a0h.w);
        a1[0] = (short)f2bf(a1l.x); a1[1] = (short)f2bf(a1l.y);
        a1[2] = (short)f2bf(a1l.z); a1[3] = (short)f2bf(a1l.w);
        a1[4] = (short)f2bf(a1h.x); a1[5] = (short)f2bf(a1h.y);
        a1[6] = (short)f2bf(a1h.z); a1[7] = (short)f2bf(a1h.w);
        bf16x8 b0 = *(const bf16x8*)(B + (size_t)(n0 + row0) * N_DIM + k0 + ko0);
        bf16x8 b1 = *(const bf16x8*)(B + (size_t)(n0 + 64 + row0) * N_DIM + k0 + ko0);
        __syncthreads();   // previous iteration's LDS readers done
        *(bf16x8*)(As + row0 * 32 + ko0)        = a0;
        *(bf16x8*)(As + (64 + row0) * 32 + ko0) = a1;
        *(bf16x8*)(Bs + row0 * 32 + ko0)        = b0;
        *(bf16x8*)(Bs + (64 + row0) * 32 + ko0) = b1;
        __syncthreads();

        bf16x8 af[4], bfr[4];
#pragma unroll
        for (int mt = 0; mt < 4; ++mt)
            af[mt] = *(const bf16x8*)(As + (wm + mt * 16 + (lane & 15)) * 32 + (lane >> 4) * 8);
#pragma unroll
        for (int nt = 0; nt < 4; ++nt)
            bfr[nt] = *(const bf16x8*)(Bs + (wn + nt * 16 + (lane & 15)) * 32 + (lane >> 4) * 8);
#pragma unroll
        for (int mt = 0; mt < 4; ++mt)
#pragma unroll
            for (int nt = 0; nt < 4; ++nt)
                acc[mt][nt] = __builtin_amdgcn_mfma_f32_16x16x32_bf16(af[mt], bfr[nt],
                                                                      acc[mt][nt], 0, 0, 0);
    }

#pragma unroll
    for (int mt = 0; mt < 4; ++mt)
#pragma unroll
        for (int nt = 0; nt < 4; ++nt) {
            const int col = n0 + wn + nt * 16 + (lane & 15);
            const float bv = bias[col];
#pragma unroll
            for (int r = 0; r < 4; ++r) {
                const int rowm = m0 + wm + mt * 16 + (lane >> 4) * 4 + r;
                const float v = acc[mt][nt][r] + bv;
                if constexpr (sizeof(GXT) == 2)
                    ((u16*)C)[(size_t)rowm * N3 + col] = f2bf(v);
                else
                    ((float*)C)[(size_t)rowm * N3 + col] = v;
            }
        }
}

// ---------------------------------------------------------------------------
// Persistent GRU scan. 128 blocks x 256 threads (cooperative launch => all
// co-resident; 1 block/CU). Block g owns h columns [g*16, g*16+16). Wh slice
// (48 rows x 2048) lives in registers: 384 fp32 per thread (AGPR+VGPR
// unified file; ~450 total regs -> 4 waves/CU, fits).
//
// Cross-block h exchange: round-0's PROVEN fabric, unchanged: tag-embedded
// 64-bit slots ((step<<32)|fp32bits), double-buffered, device-scope relaxed
// atomics — tag rides with the value, so no fences. Skew is bounded <2 steps
// by the publish/poll dependency chain, so the 2-deep ping-pong can't be
// overrun. 3 barriers/step (round-1 showed dropping one regresses 35%:
// freed waves spin on atomics during the publish window).
//
// Why 128 blocks: round-0 counters showed ~1 GB of poll fetch (~8 rounds x
// 16KB x 256 blocks per step ~ 9 TB/s at the coherence point) — the polls
// saturate the L2-miss path and inflate publish->detect latency. Halving the
// participants halves poll traffic per round and shrinks the per-step
// straggler tail; the extra dot work (+192 FMA/thread) is ~0.16us against a
// 3.5us step.
template <typename GXT>
__global__ __launch_bounds__(256, 1) void k_scan(const GXT* __restrict__ gx,
                                                 const float* __restrict__ wht,  // [6144][2048]
                                                 float* __restrict__ out,
                                                 u64* __restrict__ hbuf) {       // [2][2048]
    extern __shared__ float smem[];
    float* h_lds = smem;            // 2048 fp32
    float* red   = smem + N_DIM;    // 48 partial sums

    const int tid = threadIdx.x, lane = tid & 63, wave = tid >> 6;
    const int g = blockIdx.x;

    // Load this thread's 384 weights into registers.
    // Wave w covers local rows r = 12w..12w+11; row r -> global col
    // (r>>4)*2048 + g*16 + (r&15). Thread covers k = q*512 + lane*8 + j.
    float wreg[RPW][32];
#pragma unroll
    for (int c = 0; c < RPW; ++c) {
        const int rr = wave * RPW + c;
        const int col = (rr >> 4) * N_DIM + g * COLS + (rr & 15);
        const float* wp = wht + (size_t)col * N_DIM + lane * 8;
#pragma unroll
        for (int q = 0; q < 4; ++q) {
            f32x4 v0 = *(const f32x4*)(wp + q * 512);
            f32x4 v1 = *(const f32x4*)(wp + q * 512 + 4);
#pragma unroll
            for (int j = 0; j < 4; ++j) {
                wreg[c][q * 8 + j]     = v0[j];
                wreg[c][q * 8 + 4 + j] = v1[j];
            }
        }
    }

    for (int t = 0; t < M_SEQ; ++t) {
        u64* cur = hbuf + (size_t)(t & 1) * N_DIM;
        u64* nxt = hbuf + (size_t)((t + 1) & 1) * N_DIM;
        const unsigned int expect = (unsigned int)t;

        // Prefetch gate inputs for this step (independent of h — hides gx
        // latency under the poll below).
        float xz = 0.f, xr = 0.f, xn = 0.f;
        if (tid < COLS) {
            const GXT* gp = gx + (size_t)t * N3 + g * COLS + tid;
            if constexpr (sizeof(GXT) == 2) {
                xz = bf2f(((const u16*)gp)[0]);
                xr = bf2f(((const u16*)gp)[N_DIM]);
                xn = bf2f(((const u16*)gp)[2 * N_DIM]);
            } else {
                xz = ((const float*)gp)[0];
                xr = ((const float*)gp)[N_DIM];
                xn = ((const float*)gp)[2 * N_DIM];
            }
        }

        // Poll the 8 slots this thread stages (stride-256 => coalesced), then
        // unpack into LDS.
        {
            u64 v[8];
            for (;;) {
#pragma unroll
                for (int i = 0; i < 8; ++i)
                    v[i] = __hip_atomic_load(cur + tid + i * 256, __ATOMIC_RELAXED,
                                             __HIP_MEMORY_SCOPE_AGENT);
                bool ok = true;
#pragma unroll
                for (int i = 0; i < 8; ++i) ok &= ((unsigned int)(v[i] >> 32) == expect);
                if (ok) break;
                __builtin_amdgcn_s_sleep(1);
            }
#pragma unroll
            for (int i = 0; i < 8; ++i)
                h_lds[tid + i * 256] =
                    __builtin_bit_cast(float, (unsigned int)(v[i] & 0xffffffffu));
        }
        __syncthreads();

        // 12 dot products per thread against register weights.
        float acc[RPW] = {};
#pragma unroll
        for (int q = 0; q < 4; ++q) {
            const float* hp = h_lds + q * 512 + lane * 8;
            f32x4 h0 = *(const f32x4*)(hp);
            f32x4 h1 = *(const f32x4*)(hp + 4);
#pragma unroll
            for (int c = 0; c < RPW; ++c) {
#pragma unroll
                for (int j = 0; j < 4; ++j) {
                    acc[c] += wreg[c][q * 8 + j]     * h0[j];
                    acc[c] += wreg[c][q * 8 + 4 + j] * h1[j];
                }
            }
        }
#pragma unroll
        for (int c = 0; c < RPW; ++c) {
            float a = acc[c];
#pragma unroll
            for (int off = 32; off; off >>= 1) a += __shfl_xor(a, off, 64);
            if (lane == 0) red[wave * RPW + c] = a;
        }
        __syncthreads();

        // Gates + publish (first 16 threads).
        if (tid < COLS) {
            const float hz = red[tid], hr = red[COLS + tid], hn = red[2 * COLS + tid];
            const float h_old = h_lds[g * COLS + tid];
            const float z = 1.f / (1.f + __expf(-(xz + hz)));
            const float r = 1.f / (1.f + __expf(-(xr + hr)));
            const float a2 = xn + r * hn;
            const float cand = 1.f - 2.f / (__expf(2.f * a2) + 1.f);  // tanh(a2)
            const float hnew = (1.f - z) * h_old + z * cand;
            out[(size_t)t * N_DIM + g * COLS + tid] = hnew;
            const u64 slot = ((u64)(unsigned int)(t + 1) << 32) |
                             (u64)__builtin_bit_cast(unsigned int, hnew);
            __hip_atomic_store(nxt + g * COLS + tid, slot, __ATOMIC_RELAXED,
                               __HIP_MEMORY_SCOPE_AGENT);
        }
        __syncthreads();   // protect h_lds/red reuse next step
    }
}

// ---------------------------------------------------------------------------
extern "C" void kernel_launch(void* const* d_in, const int* in_sizes, int n_in,
                              void* d_out, int out_size, void* d_ws, size_t ws_size,
                              hipStream_t stream) {
    const float* x  = (const float*)d_in[0];
    const float* Wx = (const float*)d_in[1];
    const float* Wh = (const float*)d_in[2];
    const float* b  = (const float*)d_in[3];
    float* out = (float*)d_out;

    char* ws = (char*)d_ws;
    size_t off = 0;
    auto alloc = [&](size_t bytes) -> char* {
        char* p = ws + off;
        off += (bytes + 255) & ~(size_t)255;
        return p;
    };

    // Fixed-footprint pieces: 25.2 + 50.3 MB + 32 KB
    u16*   wxt  = (u16*)  alloc((size_t)N3 * N_DIM * sizeof(u16));
    float* wht  = (float*)alloc((size_t)N3 * N_DIM * sizeof(float));
    u64*   hbuf = (u64*)  alloc((size_t)2 * N_DIM * sizeof(u64));

    // gx tier: fp32 (201.3 MB) if workspace allows, else bf16 (100.7 MB).
    // Decision depends only on ws_size => identical work every call.
    const bool gx_f32 = ws_size >= (size_t)290 * 1024 * 1024;

    k_init<<<16, 256, 0, stream>>>(hbuf);
    k_tr_bf16<<<dim3(N3 / 32, N_DIM / 32), 256, 0, stream>>>(Wx, wxt, N_DIM, N3);
    k_tr_f32 <<<dim3(N3 / 32, N_DIM / 32), 256, 0, stream>>>(Wh, wht, N_DIM, N3);

    const unsigned smem = (N_DIM + 48) * sizeof(float);
    if (gx_f32) {
        float* gx = (float*)alloc((size_t)M_SEQ * N3 * sizeof(float));
        k_gemm<float><<<dim3(N3 / 128, M_SEQ / 128), 256, 0, stream>>>(x, wxt, b, gx);
        void* args[] = {(void*)&gx, (void*)&wht, (void*)&out, (void*)&hbuf};
        hipError_t e = hipLaunchCooperativeKernel((const void*)k_scan<float>, dim3(NBLK),
                                                  dim3(256), args, smem, stream);
        if (e != hipSuccess)
            k_scan<float><<<NBLK, 256, smem, stream>>>(gx, wht, out, hbuf);
    } else {
        u16* gx = (u16*)alloc((size_t)M_SEQ * N3 * sizeof(u16));
        k_gemm<u16><<<dim3(N3 / 128, M_SEQ / 128), 256, 0, stream>>>(x, wxt, b, gx);
        void* args[] = {(void*)&gx, (void*)&wht, (void*)&out, (void*)&hbuf};
        hipError_t e = hipLaunchCooperativeKernel((const void*)k_scan<u16>, dim3(NBLK),
                                                  dim3(256), args, smem, stream);
        if (e != hipSuccess)
            k_scan<u16><<<NBLK, 256, smem, stream>>>(gx, wht, out, hbuf);
    }
}

// Round 3
// 28420.309 us; speedup vs baseline: 1.5232x; 1.5232x over previous
//
#include <hip/hip_runtime.h>
#include <stdint.h>

#define M_SEQ 8192
#define N_DIM 2048
#define N3    (3 * N_DIM)   // 6144

// h-exchange fabric geometry (round 3): 8 replicas, 256B per publisher line.
// Slot (pub p, idx j) of replica r, buffer buf lives at u64 offset
//   buf*BUFSTRIDE + r*RSTRIDE + p*LSTRIDE + j
#define REPL          8
#define LSTRIDE       32                    // u64 per publisher (256 B: 8 used + pad)
#define RSTRIDE       (256 * LSTRIDE)       // 8192 u64 per replica (64 KB)
#define BUFSTRIDE     (REPL * RSTRIDE)      // 65536 u64 per buffer (512 KB)
#define HBUF_U64      (2 * BUFSTRIDE)       // 131072 u64 total (1 MB)

typedef short bf16x8 __attribute__((ext_vector_type(8)));   // 8 bf16 in 4 VGPRs
typedef float f32x4  __attribute__((ext_vector_type(4)));
typedef unsigned short u16;
typedef unsigned long long u64;

// fp32 -> bf16, round-to-nearest-even
__device__ __forceinline__ u16 f2bf(float f) {
    unsigned int u = __builtin_bit_cast(unsigned int, f);
    u = (u + 0x7fffu + ((u >> 16) & 1u)) >> 16;
    return (u16)u;
}
__device__ __forceinline__ float bf2f(u16 v) {
    return __builtin_bit_cast(float, (unsigned int)v << 16);
}

// ---------------------------------------------------------------------------
// in [R][C] fp32 -> out [C][R] bf16  (tiled transpose)
__global__ void k_tr_bf16(const float* __restrict__ in, u16* __restrict__ out, int R, int C) {
    __shared__ float tile[32][33];
    const int tx = threadIdx.x & 31, ty = threadIdx.x >> 5;
    const int c = blockIdx.x * 32 + tx;
#pragma unroll
    for (int k = 0; k < 4; ++k)
        tile[ty + k * 8][tx] = in[(size_t)(blockIdx.y * 32 + ty + k * 8) * C + c];
    __syncthreads();
#pragma unroll
    for (int k = 0; k < 4; ++k)
        out[(size_t)(blockIdx.x * 32 + ty + k * 8) * R + blockIdx.y * 32 + tx] =
            f2bf(tile[tx][ty + k * 8]);
}

// in [R][C] fp32 -> out [C][R] fp32
__global__ void k_tr_f32(const float* __restrict__ in, float* __restrict__ out, int R, int C) {
    __shared__ float tile[32][33];
    const int tx = threadIdx.x & 31, ty = threadIdx.x >> 5;
    const int c = blockIdx.x * 32 + tx;
#pragma unroll
    for (int k = 0; k < 4; ++k)
        tile[ty + k * 8][tx] = in[(size_t)(blockIdx.y * 32 + ty + k * 8) * C + c];
    __syncthreads();
#pragma unroll
    for (int k = 0; k < 4; ++k)
        out[(size_t)(blockIdx.x * 32 + ty + k * 8) * R + blockIdx.y * 32 + tx] =
            tile[tx][ty + k * 8];
}

// zero the whole replicated/padded hbuf: tag 0 + 0.0f == legit step-0 state.
__global__ void k_init(u64* hbuf) {
    int i = blockIdx.x * 256 + threadIdx.x;
    if (i < HBUF_U64) hbuf[i] = 0ull;
}

// ---------------------------------------------------------------------------
// gx = (bf16)x @ Wx + b : A [8192][2048] fp32 row-major (converted inline),
// B [6144][2048] bf16 (Wx^T), C [8192][6144] GXT. 128x128 tile, BK=32,
// 4 waves 2x2.
template <typename GXT>
__global__ __launch_bounds__(256) void k_gemm(const float* __restrict__ A,
                                              const u16* __restrict__ B,
                                              const float* __restrict__ bias,
                                              GXT* __restrict__ C) {
    __shared__ u16 As[128 * 32];
    __shared__ u16 Bs[128 * 32];
    const int tid = threadIdx.x, lane = tid & 63, wave = tid >> 6;
    const int m0 = blockIdx.y * 128, n0 = blockIdx.x * 128;
    const int wm = (wave >> 1) * 64, wn = (wave & 1) * 64;
    const int row0 = tid >> 2, ko0 = (tid & 3) * 8;   // 8 elems (16B bf16) per thread/half

    f32x4 acc[4][4] = {};

    for (int k0 = 0; k0 < N_DIM; k0 += 32) {
        // A: fp32 source, convert to bf16 in-register
        const float* ap0 = A + (size_t)(m0 + row0) * N_DIM + k0 + ko0;
        const float* ap1 = A + (size_t)(m0 + 64 + row0) * N_DIM + k0 + ko0;
        float4 a0l = *(const float4*)(ap0), a0h = *(const float4*)(ap0 + 4);
        float4 a1l = *(const float4*)(ap1), a1h = *(const float4*)(ap1 + 4);
        bf16x8 a0, a1;
        a0[0] = (short)f2bf(a0l.x); a0[1] = (short)f2bf(a0l.y);
        a0[2] = (short)f2bf(a0l.z); a0[3] = (short)f2bf(a0l.w);
        a0[4] = (short)f2bf(a0h.x); a0[5] = (short)f2bf(a0h.y);
        a0[6] = (short)f2bf(a0h.z); a0[7] = (short)f2bf(a0h.w);
        a1[0] = (short)f2bf(a1l.x); a1[1] = (short)f2bf(a1l.y);
        a1[2] = (short)f2bf(a1l.z); a1[3] = (short)f2bf(a1l.w);
        a1[4] = (short)f2bf(a1h.x); a1[5] = (short)f2bf(a1h.y);
        a1[6] = (short)f2bf(a1h.z); a1[7] = (short)f2bf(a1h.w);
        bf16x8 b0 = *(const bf16x8*)(B + (size_t)(n0 + row0) * N_DIM + k0 + ko0);
        bf16x8 b1 = *(const bf16x8*)(B + (size_t)(n0 + 64 + row0) * N_DIM + k0 + ko0);
        __syncthreads();   // previous iteration's LDS readers done
        *(bf16x8*)(As + row0 * 32 + ko0)        = a0;
        *(bf16x8*)(As + (64 + row0) * 32 + ko0) = a1;
        *(bf16x8*)(Bs + row0 * 32 + ko0)        = b0;
        *(bf16x8*)(Bs + (64 + row0) * 32 + ko0) = b1;
        __syncthreads();

        bf16x8 af[4], bfr[4];
#pragma unroll
        for (int mt = 0; mt < 4; ++mt)
            af[mt] = *(const bf16x8*)(As + (wm + mt * 16 + (lane & 15)) * 32 + (lane >> 4) * 8);
#pragma unroll
        for (int nt = 0; nt < 4; ++nt)
            bfr[nt] = *(const bf16x8*)(Bs + (wn + nt * 16 + (lane & 15)) * 32 + (lane >> 4) * 8);
#pragma unroll
        for (int mt = 0; mt < 4; ++mt)
#pragma unroll
            for (int nt = 0; nt < 4; ++nt)
                acc[mt][nt] = __builtin_amdgcn_mfma_f32_16x16x32_bf16(af[mt], bfr[nt],
                                                                      acc[mt][nt], 0, 0, 0);
    }

#pragma unroll
    for (int mt = 0; mt < 4; ++mt)
#pragma unroll
        for (int nt = 0; nt < 4; ++nt) {
            const int col = n0 + wn + nt * 16 + (lane & 15);
            const float bv = bias[col];
#pragma unroll
            for (int r = 0; r < 4; ++r) {
                const int rowm = m0 + wm + mt * 16 + (lane >> 4) * 4 + r;
                const float v = acc[mt][nt][r] + bv;
                if constexpr (sizeof(GXT) == 2)
                    ((u16*)C)[(size_t)rowm * N3 + col] = f2bf(v);
                else
                    ((float*)C)[(size_t)rowm * N3 + col] = v;
            }
        }
}

// ---------------------------------------------------------------------------
// Persistent GRU scan. 256 blocks x 256 threads (cooperative launch => all
// co-resident; 1 block/CU). Block g owns h columns [g*8, g*8+8). Wh slice
// (24 cols x 2048) lives in VGPRs: 192 fp32 per thread. Protocol, barriers,
// dot, reduce, gates: byte-identical to the proven 29.2ms round-0 kernel.
//
// Round-3 change (exchange FABRIC only): the published h state is REPLICATED
// 8x with 256B-per-publisher padding. Rationale: round-0's hbuf was 256 hot
// 64B lines, each polled by 2048 threads (8/block x 256 blocks) every poll
// round; same-line requests serialize at the coherence point (~2-4cyc each
// => ~2us/round), which matches the ~3us/step of non-compute time. Consumer
// block b polls only replica b>>5 => per-line pollers drop 8x (2048 -> 256),
// and the padded layout spreads the region over 64KB of MALL channels.
// Publishers write all 8 replicas (8 pipelined stores, latency-hidden).
//
// Skew safety is unchanged: a publisher overwrites any replica slot of step
// t (buffer t&1) only at step t+2, which requires it observed every block's
// t+1 publish, which postdates every consumer's read of its own replica at
// step t. Tag rides with the value; no fences needed.
template <typename GXT>
__global__ __launch_bounds__(256, 1) void k_scan(const GXT* __restrict__ gx,
                                                 const float* __restrict__ wht,  // [6144][2048]
                                                 float* __restrict__ out,
                                                 u64* __restrict__ hbuf) {
    extern __shared__ float smem[];
    float* h_lds = smem;            // 2048 fp32
    float* red   = smem + N_DIM;    // 24 partial sums

    const int tid = threadIdx.x, lane = tid & 63, wave = tid >> 6;
    const int g = blockIdx.x;

    // Replica this block polls, and this thread's fixed intra-replica offset.
    // Slot s = tid + 256*i  ->  pub = (tid>>3) + 32*i, idx = tid&7
    // => u64 offset = ((tid>>3) + 32*i)*LSTRIDE + (tid&7) = poff + i*1024.
    const size_t rbase = (size_t)(g >> 5) * RSTRIDE;
    const size_t poff  = (size_t)(tid >> 3) * LSTRIDE + (tid & 7);

    // Load this thread's 192 weights into registers.
    // Wave w covers local rows r = 6w..6w+5; row r -> global col
    // (r>>3)*2048 + g*8 + (r&7). Thread covers k = q*512 + lane*8 + j.
    float wreg[6][32];
#pragma unroll
    for (int c = 0; c < 6; ++c) {
        const int rr = wave * 6 + c;
        const int col = (rr >> 3) * N_DIM + g * 8 + (rr & 7);
        const float* wp = wht + (size_t)col * N_DIM + lane * 8;
#pragma unroll
        for (int q = 0; q < 4; ++q) {
            f32x4 v0 = *(const f32x4*)(wp + q * 512);
            f32x4 v1 = *(const f32x4*)(wp + q * 512 + 4);
#pragma unroll
            for (int j = 0; j < 4; ++j) {
                wreg[c][q * 8 + j]     = v0[j];
                wreg[c][q * 8 + 4 + j] = v1[j];
            }
        }
    }

    for (int t = 0; t < M_SEQ; ++t) {
        const u64* cur = hbuf + (size_t)(t & 1) * BUFSTRIDE + rbase + poff;
        u64*       nxt = hbuf + (size_t)((t + 1) & 1) * BUFSTRIDE;
        const unsigned int expect = (unsigned int)t;

        // Prefetch gate inputs for this step (independent of h — hides gx
        // latency under the poll below).
        float xz = 0.f, xr = 0.f, xn = 0.f;
        if (tid < 8) {
            const GXT* gp = gx + (size_t)t * N3 + g * 8 + tid;
            if constexpr (sizeof(GXT) == 2) {
                xz = bf2f(((const u16*)gp)[0]);
                xr = bf2f(((const u16*)gp)[N_DIM]);
                xn = bf2f(((const u16*)gp)[2 * N_DIM]);
            } else {
                xz = ((const float*)gp)[0];
                xr = ((const float*)gp)[N_DIM];
                xn = ((const float*)gp)[2 * N_DIM];
            }
        }

        // Poll the 8 slots this thread stages, then unpack into LDS.
        {
            u64 v[8];
            for (;;) {
#pragma unroll
                for (int i = 0; i < 8; ++i)
                    v[i] = __hip_atomic_load(cur + (size_t)i * (32 * LSTRIDE),
                                             __ATOMIC_RELAXED, __HIP_MEMORY_SCOPE_AGENT);
                bool ok = true;
#pragma unroll
                for (int i = 0; i < 8; ++i) ok &= ((unsigned int)(v[i] >> 32) == expect);
                if (ok) break;
                __builtin_amdgcn_s_sleep(1);
            }
#pragma unroll
            for (int i = 0; i < 8; ++i)
                h_lds[tid + i * 256] =
                    __builtin_bit_cast(float, (unsigned int)(v[i] & 0xffffffffu));
        }
        __syncthreads();

        // 6 dot products per thread against register weights.
        float acc[6] = {};
#pragma unroll
        for (int q = 0; q < 4; ++q) {
            const float* hp = h_lds + q * 512 + lane * 8;
            f32x4 h0 = *(const f32x4*)(hp);
            f32x4 h1 = *(const f32x4*)(hp + 4);
#pragma unroll
            for (int c = 0; c < 6; ++c) {
#pragma unroll
                for (int j = 0; j < 4; ++j) {
                    acc[c] += wreg[c][q * 8 + j]     * h0[j];
                    acc[c] += wreg[c][q * 8 + 4 + j] * h1[j];
                }
            }
        }
#pragma unroll
        for (int c = 0; c < 6; ++c) {
            float a = acc[c];
#pragma unroll
            for (int off = 32; off; off >>= 1) a += __shfl_xor(a, off, 64);
            if (lane == 0) red[wave * 6 + c] = a;
        }
        __syncthreads();

        // Gates + publish (lanes 0..7 of wave 0). Publish stores issued
        // FIRST (critical path), 'out' store after.
        if (tid < 8) {
            const float hz = red[tid], hr = red[8 + tid], hn = red[16 + tid];
            const float h_old = h_lds[g * 8 + tid];
            const float z = 1.f / (1.f + __expf(-(xz + hz)));
            const float r = 1.f / (1.f + __expf(-(xr + hr)));
            const float a2 = xn + r * hn;
            const float cand = 1.f - 2.f / (__expf(2.f * a2) + 1.f);  // tanh(a2)
            const float hnew = (1.f - z) * h_old + z * cand;
            const u64 slot = ((u64)(unsigned int)(t + 1) << 32) |
                             (u64)__builtin_bit_cast(unsigned int, hnew);
            u64* np = nxt + (size_t)g * LSTRIDE + tid;
#pragma unroll
            for (int r8 = 0; r8 < REPL; ++r8)
                __hip_atomic_store(np + (size_t)r8 * RSTRIDE, slot, __ATOMIC_RELAXED,
                                   __HIP_MEMORY_SCOPE_AGENT);
            out[(size_t)t * N_DIM + g * 8 + tid] = hnew;
        }
        __syncthreads();   // protect h_lds/red reuse next step
    }
}

// ---------------------------------------------------------------------------
extern "C" void kernel_launch(void* const* d_in, const int* in_sizes, int n_in,
                              void* d_out, int out_size, void* d_ws, size_t ws_size,
                              hipStream_t stream) {
    const float* x  = (const float*)d_in[0];
    const float* Wx = (const float*)d_in[1];
    const float* Wh = (const float*)d_in[2];
    const float* b  = (const float*)d_in[3];
    float* out = (float*)d_out;

    char* ws = (char*)d_ws;
    size_t off = 0;
    auto alloc = [&](size_t bytes) -> char* {
        char* p = ws + off;
        off += (bytes + 255) & ~(size_t)255;
        return p;
    };

    // Fixed-footprint pieces: 25.2 + 50.3 + 1.0 MB
    u16*   wxt  = (u16*)  alloc((size_t)N3 * N_DIM * sizeof(u16));
    float* wht  = (float*)alloc((size_t)N3 * N_DIM * sizeof(float));
    u64*   hbuf = (u64*)  alloc((size_t)HBUF_U64 * sizeof(u64));

    // gx tier: fp32 (201.3 MB) if workspace allows, else bf16 (100.7 MB).
    // Decision depends only on ws_size => identical work every call.
    const bool gx_f32 = ws_size >= (size_t)290 * 1024 * 1024;

    k_init<<<HBUF_U64 / 256, 256, 0, stream>>>(hbuf);
    k_tr_bf16<<<dim3(N3 / 32, N_DIM / 32), 256, 0, stream>>>(Wx, wxt, N_DIM, N3);
    k_tr_f32 <<<dim3(N3 / 32, N_DIM / 32), 256, 0, stream>>>(Wh, wht, N_DIM, N3);

    const unsigned smem = (N_DIM + 32) * sizeof(float);
    if (gx_f32) {
        float* gx = (float*)alloc((size_t)M_SEQ * N3 * sizeof(float));
        k_gemm<float><<<dim3(N3 / 128, M_SEQ / 128), 256, 0, stream>>>(x, wxt, b, gx);
        void* args[] = {(void*)&gx, (void*)&wht, (void*)&out, (void*)&hbuf};
        hipError_t e = hipLaunchCooperativeKernel((const void*)k_scan<float>, dim3(256),
                                                  dim3(256), args, smem, stream);
        if (e != hipSuccess)
            k_scan<float><<<256, 256, smem, stream>>>(gx, wht, out, hbuf);
    } else {
        u16* gx = (u16*)alloc((size_t)M_SEQ * N3 * sizeof(u16));
        k_gemm<u16><<<dim3(N3 / 128, M_SEQ / 128), 256, 0, stream>>>(x, wxt, b, gx);
        void* args[] = {(void*)&gx, (void*)&wht, (void*)&out, (void*)&hbuf};
        hipError_t e = hipLaunchCooperativeKernel((const void*)k_scan<u16>, dim3(256),
                                                  dim3(256), args, smem, stream);
        if (e != hipSuccess)
            k_scan<u16><<<256, 256, smem, stream>>>(gx, wht, out, hbuf);
    }
}

// Round 6
// 22688.615 us; speedup vs baseline: 1.9079x; 1.2526x over previous
//
#include <hip/hip_runtime.h>
#include <stdint.h>

#define M_SEQ 8192
#define N_DIM 2048
#define N3    (3 * N_DIM)   // 6144

// h-exchange fabric geometry (unchanged from round 3): 8 replicas, 256B per
// publisher line. Slot (pub p, idx j) of replica r, buffer buf lives at u64
// offset buf*BUFSTRIDE + r*RSTRIDE + p*LSTRIDE + j
#define REPL          8
#define LSTRIDE       32                    // u64 per publisher (256 B: 8 used + pad)
#define RSTRIDE       (256 * LSTRIDE)       // 8192 u64 per replica (64 KB)
#define BUFSTRIDE     (REPL * RSTRIDE)      // 65536 u64 per buffer (512 KB)
#define HBUF_U64      (2 * BUFSTRIDE)       // 131072 u64 total (1 MB)

// Spin guard: converts any (hypothetical) protocol deadlock into a fast
// terminating run with wrong data (=> passed:false signal) instead of a
// dead container. Scalar-only cost in the poll loop; never fires in a
// correct run (normal spins are ~10 rounds).
#define SPIN_LIMIT    16384

typedef short bf16x8 __attribute__((ext_vector_type(8)));   // 8 bf16 in 4 VGPRs
typedef float f32x4  __attribute__((ext_vector_type(4)));
typedef unsigned short u16;
typedef unsigned long long u64;

// fp32 -> bf16, round-to-nearest-even
__device__ __forceinline__ u16 f2bf(float f) {
    unsigned int u = __builtin_bit_cast(unsigned int, f);
    u = (u + 0x7fffu + ((u >> 16) & 1u)) >> 16;
    return (u16)u;
}
__device__ __forceinline__ float bf2f(u16 v) {
    return __builtin_bit_cast(float, (unsigned int)v << 16);
}

// ---------------------------------------------------------------------------
// in [R][C] fp32 -> out [C][R] bf16  (tiled transpose)
__global__ void k_tr_bf16(const float* __restrict__ in, u16* __restrict__ out, int R, int C) {
    __shared__ float tile[32][33];
    const int tx = threadIdx.x & 31, ty = threadIdx.x >> 5;
    const int c = blockIdx.x * 32 + tx;
#pragma unroll
    for (int k = 0; k < 4; ++k)
        tile[ty + k * 8][tx] = in[(size_t)(blockIdx.y * 32 + ty + k * 8) * C + c];
    __syncthreads();
#pragma unroll
    for (int k = 0; k < 4; ++k)
        out[(size_t)(blockIdx.x * 32 + ty + k * 8) * R + blockIdx.y * 32 + tx] =
            f2bf(tile[tx][ty + k * 8]);
}

// in [R][C] fp32 -> out [C][R] fp32
__global__ void k_tr_f32(const float* __restrict__ in, float* __restrict__ out, int R, int C) {
    __shared__ float tile[32][33];
    const int tx = threadIdx.x & 31, ty = threadIdx.x >> 5;
    const int c = blockIdx.x * 32 + tx;
#pragma unroll
    for (int k = 0; k < 4; ++k)
        tile[ty + k * 8][tx] = in[(size_t)(blockIdx.y * 32 + ty + k * 8) * C + c];
    __syncthreads();
#pragma unroll
    for (int k = 0; k < 4; ++k)
        out[(size_t)(blockIdx.x * 32 + ty + k * 8) * R + blockIdx.y * 32 + tx] =
            tile[tx][ty + k * 8];
}

// zero the whole replicated/padded hbuf: tag 0 + 0.0f == legit step-0 state.
__global__ void k_init(u64* hbuf) {
    int i = blockIdx.x * 256 + threadIdx.x;
    if (i < HBUF_U64) hbuf[i] = 0ull;
}

// ---------------------------------------------------------------------------
// gx = (bf16)x @ Wx + b : A [8192][2048] fp32 row-major (converted inline),
// B [6144][2048] bf16 (Wx^T), C [8192][6144] GXT. 128x128 tile, BK=32,
// 4 waves 2x2.
template <typename GXT>
__global__ __launch_bounds__(256) void k_gemm(const float* __restrict__ A,
                                              const u16* __restrict__ B,
                                              const float* __restrict__ bias,
                                              GXT* __restrict__ C) {
    __shared__ u16 As[128 * 32];
    __shared__ u16 Bs[128 * 32];
    const int tid = threadIdx.x, lane = tid & 63, wave = tid >> 6;
    const int m0 = blockIdx.y * 128, n0 = blockIdx.x * 128;
    const int wm = (wave >> 1) * 64, wn = (wave & 1) * 64;
    const int row0 = tid >> 2, ko0 = (tid & 3) * 8;   // 8 elems (16B bf16) per thread/half

    f32x4 acc[4][4] = {};

    for (int k0 = 0; k0 < N_DIM; k0 += 32) {
        // A: fp32 source, convert to bf16 in-register
        const float* ap0 = A + (size_t)(m0 + row0) * N_DIM + k0 + ko0;
        const float* ap1 = A + (size_t)(m0 + 64 + row0) * N_DIM + k0 + ko0;
        float4 a0l = *(const float4*)(ap0), a0h = *(const float4*)(ap0 + 4);
        float4 a1l = *(const float4*)(ap1), a1h = *(const float4*)(ap1 + 4);
        bf16x8 a0, a1;
        a0[0] = (short)f2bf(a0l.x); a0[1] = (short)f2bf(a0l.y);
        a0[2] = (short)f2bf(a0l.z); a0[3] = (short)f2bf(a0l.w);
        a0[4] = (short)f2bf(a0h.x); a0[5] = (short)f2bf(a0h.y);
        a0[6] = (short)f2bf(a0h.z); a0[7] = (short)f2bf(a0h.w);
        a1[0] = (short)f2bf(a1l.x); a1[1] = (short)f2bf(a1l.y);
        a1[2] = (short)f2bf(a1l.z); a1[3] = (short)f2bf(a1l.w);
        a1[4] = (short)f2bf(a1h.x); a1[5] = (short)f2bf(a1h.y);
        a1[6] = (short)f2bf(a1h.z); a1[7] = (short)f2bf(a1h.w);
        bf16x8 b0 = *(const bf16x8*)(B + (size_t)(n0 + row0) * N_DIM + k0 + ko0);
        bf16x8 b1 = *(const bf16x8*)(B + (size_t)(n0 + 64 + row0) * N_DIM + k0 + ko0);
        __syncthreads();   // previous iteration's LDS readers done
        *(bf16x8*)(As + row0 * 32 + ko0)        = a0;
        *(bf16x8*)(As + (64 + row0) * 32 + ko0) = a1;
        *(bf16x8*)(Bs + row0 * 32 + ko0)        = b0;
        *(bf16x8*)(Bs + (64 + row0) * 32 + ko0) = b1;
        __syncthreads();

        bf16x8 af[4], bfr[4];
#pragma unroll
        for (int mt = 0; mt < 4; ++mt)
            af[mt] = *(const bf16x8*)(As + (wm + mt * 16 + (lane & 15)) * 32 + (lane >> 4) * 8);
#pragma unroll
        for (int nt = 0; nt < 4; ++nt)
            bfr[nt] = *(const bf16x8*)(Bs + (wn + nt * 16 + (lane & 15)) * 32 + (lane >> 4) * 8);
#pragma unroll
        for (int mt = 0; mt < 4; ++mt)
#pragma unroll
            for (int nt = 0; nt < 4; ++nt)
                acc[mt][nt] = __builtin_amdgcn_mfma_f32_16x16x32_bf16(af[mt], bfr[nt],
                                                                      acc[mt][nt], 0, 0, 0);
    }

#pragma unroll
    for (int mt = 0; mt < 4; ++mt)
#pragma unroll
        for (int nt = 0; nt < 4; ++nt) {
            const int col = n0 + wn + nt * 16 + (lane & 15);
            const float bv = bias[col];
#pragma unroll
            for (int r = 0; r < 4; ++r) {
                const int rowm = m0 + wm + mt * 16 + (lane >> 4) * 4 + r;
                const float v = acc[mt][nt][r] + bv;
                if constexpr (sizeof(GXT) == 2)
                    ((u16*)C)[(size_t)rowm * N3 + col] = f2bf(v);
                else
                    ((float*)C)[(size_t)rowm * N3 + col] = v;
            }
        }
}

// ---------------------------------------------------------------------------
// Persistent GRU scan. 256 blocks x 256 threads (cooperative launch => all
// co-resident; 1 block/CU). Block g owns h columns [g*8, g*8+8). Wh slice
// (24 gate-rows x 2048) lives in VGPRs: 192 fp32 per thread. Exchange fabric
// is round-3's (8x replicated, 256B-padded, tag-embedded 64-bit slots,
// relaxed agent-scope atomics; skew bound <2 steps by the dependency chain).
//
// Round-4 experiment (intra-block back half): gate-rows remapped so each
// h-column's {z,r,n} rows live in ONE wave. Wave w owns rows
// {2w, 2w+1, 8+2w, 9+2w, 16+2w, 17+2w} (columns 2w, 2w+1). The 64-lane
// butterfly reduce leaves every row-sum in ALL lanes, so lanes 0,1 of each
// wave hold the complete {hz,hr,hn} for their own column =>
//   - gates computed 8-way parallel (was 8 threads of wave 0, serial tail)
//   - no red[] LDS round trip, no middle barrier: 2 barriers/step (was 3)
//   - final-barrier wait is symmetric across waves (no idle-wave window).
template <typename GXT>
__global__ __launch_bounds__(256, 1) void k_scan(const GXT* __restrict__ gx,
                                                 const float* __restrict__ wht,  // [6144][2048]
                                                 float* __restrict__ out,
                                                 u64* __restrict__ hbuf) {
    extern __shared__ float smem[];
    float* h_lds = smem;            // 2048 fp32

    const int tid = threadIdx.x, lane = tid & 63, wave = tid >> 6;
    const int g = blockIdx.x;

    // Replica this block polls, and this thread's fixed intra-replica offset.
    // Slot s = tid + 256*i  ->  pub = (tid>>3) + 32*i, idx = tid&7
    // => u64 offset = ((tid>>3) + 32*i)*LSTRIDE + (tid&7) = poff + i*1024.
    const size_t rbase = (size_t)(g >> 5) * RSTRIDE;
    const size_t poff  = (size_t)(tid >> 3) * LSTRIDE + (tid & 7);

    // This wave's column pair; lanes 0,1 own one column each.
    const int cc = 2 * wave + (lane & 1);       // local column for gate phase
    const bool gate_lane = (lane < 2);

    // Load this thread's 192 weights into registers.
    // Local slot c (0..5) -> gate-row rr = (c>>1)*8 + 2*wave + (c&1)
    //   (c=0,1: z rows for cols 2w,2w+1; c=2,3: r rows; c=4,5: n rows)
    // Row rr -> global col (rr>>3)*2048 + g*8 + (rr&7). Thread covers
    // k = q*512 + lane*8 + j.
    float wreg[6][32];
#pragma unroll
    for (int c = 0; c < 6; ++c) {
        const int rr = (c >> 1) * 8 + 2 * wave + (c & 1);
        const int col = (rr >> 3) * N_DIM + g * 8 + (rr & 7);
        const float* wp = wht + (size_t)col * N_DIM + lane * 8;
#pragma unroll
        for (int q = 0; q < 4; ++q) {
            f32x4 v0 = *(const f32x4*)(wp + q * 512);
            f32x4 v1 = *(const f32x4*)(wp + q * 512 + 4);
#pragma unroll
            for (int j = 0; j < 4; ++j) {
                wreg[c][q * 8 + j]     = v0[j];
                wreg[c][q * 8 + 4 + j] = v1[j];
            }
        }
    }

    for (int t = 0; t < M_SEQ; ++t) {
        const u64* cur = hbuf + (size_t)(t & 1) * BUFSTRIDE + rbase + poff;
        u64*       nxt = hbuf + (size_t)((t + 1) & 1) * BUFSTRIDE;
        const unsigned int expect = (unsigned int)t;

        // Prefetch gate inputs for this step (independent of h — hides gx
        // latency under the poll below). Done by the gate lanes themselves.
        float xz = 0.f, xr = 0.f, xn = 0.f;
        if (gate_lane) {
            const GXT* gp = gx + (size_t)t * N3 + g * 8 + cc;
            if constexpr (sizeof(GXT) == 2) {
                xz = bf2f(((const u16*)gp)[0]);
                xr = bf2f(((const u16*)gp)[N_DIM]);
                xn = bf2f(((const u16*)gp)[2 * N_DIM]);
            } else {
                xz = ((const float*)gp)[0];
                xr = ((const float*)gp)[N_DIM];
                xn = ((const float*)gp)[2 * N_DIM];
            }
        }

        // Poll the 8 slots this thread stages, then unpack into LDS.
        // SPIN_LIMIT guard: scalar-only; never fires in a correct run.
        {
            u64 v[8];
            int guard = 0;
            for (;;) {
#pragma unroll
                for (int i = 0; i < 8; ++i)
                    v[i] = __hip_atomic_load(cur + (size_t)i * (32 * LSTRIDE),
                                             __ATOMIC_RELAXED, __HIP_MEMORY_SCOPE_AGENT);
                bool ok = true;
#pragma unroll
                for (int i = 0; i < 8; ++i) ok &= ((unsigned int)(v[i] >> 32) == expect);
                if (ok || ++guard > SPIN_LIMIT) break;
                __builtin_amdgcn_s_sleep(1);
            }
#pragma unroll
            for (int i = 0; i < 8; ++i)
                h_lds[tid + i * 256] =
                    __builtin_bit_cast(float, (unsigned int)(v[i] & 0xffffffffu));
        }
        __syncthreads();   // h_lds fully staged

        // 6 dot products per thread against register weights.
        float acc[6] = {};
#pragma unroll
        for (int q = 0; q < 4; ++q) {
            const float* hp = h_lds + q * 512 + lane * 8;
            f32x4 h0 = *(const f32x4*)(hp);
            f32x4 h1 = *(const f32x4*)(hp + 4);
#pragma unroll
            for (int c = 0; c < 6; ++c) {
#pragma unroll
                for (int j = 0; j < 4; ++j) {
                    acc[c] += wreg[c][q * 8 + j]     * h0[j];
                    acc[c] += wreg[c][q * 8 + 4 + j] * h1[j];
                }
            }
        }
        // Butterfly: every lane ends with the full 64-lane sum of each row.
#pragma unroll
        for (int c = 0; c < 6; ++c) {
#pragma unroll
            for (int off = 32; off; off >>= 1) acc[c] += __shfl_xor(acc[c], off, 64);
        }

        // Gates + publish: lanes 0,1 of EVERY wave, one column each.
        // acc[lane&1]=hz, acc[2+(lane&1)]=hr, acc[4+(lane&1)]=hn for col cc.
        if (gate_lane) {
            const int l = lane;                  // 0 or 1
            const float hz = acc[l], hr = acc[2 + l], hn = acc[4 + l];
            const float h_old = h_lds[g * 8 + cc];
            const float z = 1.f / (1.f + __expf(-(xz + hz)));
            const float r = 1.f / (1.f + __expf(-(xr + hr)));
            const float a2 = xn + r * hn;
            const float cand = 1.f - 2.f / (__expf(2.f * a2) + 1.f);  // tanh(a2)
            const float hnew = (1.f - z) * h_old + z * cand;
            const u64 slot = ((u64)(unsigned int)(t + 1) << 32) |
                             (u64)__builtin_bit_cast(unsigned int, hnew);
            u64* np = nxt + (size_t)g * LSTRIDE + cc;
#pragma unroll
            for (int r8 = 0; r8 < REPL; ++r8)
                __hip_atomic_store(np + (size_t)r8 * RSTRIDE, slot, __ATOMIC_RELAXED,
                                   __HIP_MEMORY_SCOPE_AGENT);
            out[(size_t)t * N_DIM + g * 8 + cc] = hnew;
        }
        __syncthreads();   // all dot reads + publishes done before next unpack
    }
}

// ---------------------------------------------------------------------------
extern "C" void kernel_launch(void* const* d_in, const int* in_sizes, int n_in,
                              void* d_out, int out_size, void* d_ws, size_t ws_size,
                              hipStream_t stream) {
    const float* x  = (const float*)d_in[0];
    const float* Wx = (const float*)d_in[1];
    const float* Wh = (const float*)d_in[2];
    const float* b  = (const float*)d_in[3];
    float* out = (float*)d_out;

    char* ws = (char*)d_ws;
    size_t off = 0;
    auto alloc = [&](size_t bytes) -> char* {
        char* p = ws + off;
        off += (bytes + 255) & ~(size_t)255;
        return p;
    };

    // Fixed-footprint pieces: 25.2 + 50.3 + 1.0 MB
    u16*   wxt  = (u16*)  alloc((size_t)N3 * N_DIM * sizeof(u16));
    float* wht  = (float*)alloc((size_t)N3 * N_DIM * sizeof(float));
    u64*   hbuf = (u64*)  alloc((size_t)HBUF_U64 * sizeof(u64));

    // gx tier: fp32 (201.3 MB) if workspace allows, else bf16 (100.7 MB).
    // Decision depends only on ws_size => identical work every call.
    const bool gx_f32 = ws_size >= (size_t)290 * 1024 * 1024;

    k_init<<<HBUF_U64 / 256, 256, 0, stream>>>(hbuf);
    k_tr_bf16<<<dim3(N3 / 32, N_DIM / 32), 256, 0, stream>>>(Wx, wxt, N_DIM, N3);
    k_tr_f32 <<<dim3(N3 / 32, N_DIM / 32), 256, 0, stream>>>(Wh, wht, N_DIM, N3);

    const unsigned smem = N_DIM * sizeof(float);
    if (gx_f32) {
        float* gx = (float*)alloc((size_t)M_SEQ * N3 * sizeof(float));
        k_gemm<float><<<dim3(N3 / 128, M_SEQ / 128), 256, 0, stream>>>(x, wxt, b, gx);
        void* args[] = {(void*)&gx, (void*)&wht, (void*)&out, (void*)&hbuf};
        hipError_t e = hipLaunchCooperativeKernel((const void*)k_scan<float>, dim3(256),
                                                  dim3(256), args, smem, stream);
        if (e != hipSuccess)
            k_scan<float><<<256, 256, smem, stream>>>(gx, wht, out, hbuf);
    } else {
        u16* gx = (u16*)alloc((size_t)M_SEQ * N3 * sizeof(u16));
        k_gemm<u16><<<dim3(N3 / 128, M_SEQ / 128), 256, 0, stream>>>(x, wxt, b, gx);
        void* args[] = {(void*)&gx, (void*)&wht, (void*)&out, (void*)&hbuf};
        hipError_t e = hipLaunchCooperativeKernel((const void*)k_scan<u16>, dim3(256),
                                                  dim3(256), args, smem, stream);
        if (e != hipSuccess)
            k_scan<u16><<<256, 256, smem, stream>>>(gx, wht, out, hbuf);
    }
}